// Round 3
// baseline (477.371 us; speedup 1.0000x reference)
//
#include <hip/hip_runtime.h>

// Leaky integrator: out[t] = BETA*out[t-1] + x[t], x: (T=2048, B=32, D=1024) f32.
// R5: occupancy fix. R4's float4 halved the grid to 1024 one-wave blocks
// (1 wave/SIMD -> zero TLP, 3.8us per 8-step batch, 31% HBM). VGPR=40 proved
// the ping-pong double-buffer was collapsed by the regalloc anyway.
//  - keep float4 + NT stores (L3 absorbed 180 MB of warm re-reads in R4)
//  - NCH=16 (CHUNK=128, WARM=128): 2048 one-wave blocks = 8 waves/CU,
//    2 waves/SIMD -> load-wait of one wave overlaps consume of the other
//  - simple batch-load-then-consume (R2 structure); TLP does the hiding
//  - warm redundancy 15x128 steps = 240 MB issued reads, mostly L3 hits
//    (all 2048 blocks co-resident: chunk y warm reads = chunk y-1 main reads)

constexpr int   T_DIM = 2048;
constexpr int   BD    = 32 * 1024;     // 32768 scalar channels
constexpr int   BD4   = BD / 4;        // 8192 float4 channels
constexpr float BETA  = 0.95f;
constexpr int   CHUNK = 128;           // time steps per block
constexpr int   WARM  = 128;           // warm-up steps (beta^128 ~ 1.4e-3)
constexpr int   NCH   = T_DIM / CHUNK; // 16
constexpr int   BLOCK = 64;
constexpr int   G     = 8;             // load-batch depth (8 KB/wave in flight)

typedef float nt_f4 __attribute__((ext_vector_type(4)));  // native vec for NT store

__global__ __launch_bounds__(BLOCK)
void li_kernel(const float4* __restrict__ x, float4* __restrict__ out) {
    const int c  = blockIdx.x * BLOCK + threadIdx.x;  // float4 channel
    const int t0 = blockIdx.y * CHUNK;

    float b0 = 0.0f, b1 = 0.0f, b2 = 0.0f, b3 = 0.0f;

    // ---- warm-up: read-only scan of the preceding WARM steps ----
    if (blockIdx.y > 0) {
        const float4* px = x + (size_t)(t0 - WARM) * BD4 + c;
        for (int g = 0; g < WARM / G; ++g) {
            float4 v[G];
            #pragma unroll
            for (int i = 0; i < G; ++i) v[i] = px[(size_t)i * BD4];
            #pragma unroll
            for (int i = 0; i < G; ++i) {
                b0 = fmaf(BETA, b0, v[i].x);
                b1 = fmaf(BETA, b1, v[i].y);
                b2 = fmaf(BETA, b2, v[i].z);
                b3 = fmaf(BETA, b3, v[i].w);
            }
            px += (size_t)G * BD4;
        }
    }

    // ---- main: scan CHUNK steps, store running state ----
    const float4* px = x   + (size_t)t0 * BD4 + c;
    float4*       po = out + (size_t)t0 * BD4 + c;
    for (int g = 0; g < CHUNK / G; ++g) {
        float4 v[G];
        #pragma unroll
        for (int i = 0; i < G; ++i) v[i] = px[(size_t)i * BD4];
        #pragma unroll
        for (int i = 0; i < G; ++i) {
            b0 = fmaf(BETA, b0, v[i].x);
            b1 = fmaf(BETA, b1, v[i].y);
            b2 = fmaf(BETA, b2, v[i].z);
            b3 = fmaf(BETA, b3, v[i].w);
            nt_f4 vv = {b0, b1, b2, b3};
            __builtin_nontemporal_store(
                vv, reinterpret_cast<nt_f4*>(po + (size_t)i * BD4));
        }
        px += (size_t)G * BD4;
        po += (size_t)G * BD4;
    }
}

extern "C" void kernel_launch(void* const* d_in, const int* in_sizes, int n_in,
                              void* d_out, int out_size, void* d_ws, size_t ws_size,
                              hipStream_t stream) {
    const float4* x   = (const float4*)d_in[0];
    float4*       out = (float4*)d_out;

    dim3 block(BLOCK, 1, 1);
    dim3 grid(BD4 / BLOCK, NCH, 1);   // (128, 16) = 2048 blocks, 8 waves/CU
    li_kernel<<<grid, block, 0, stream>>>(x, out);
}

// Round 6
// 468.610 us; speedup vs baseline: 1.0187x; 1.0187x over previous
//
#include <hip/hip_runtime.h>

// Leaky integrator: out[t] = BETA*out[t-1] + x[t], x: (T=2048, B=32, D=1024) f32.
// R8 = R6/R7 hypothesis (depth-4 pin-forced rolling prefetch), fence count
// halved: sched_barrier(0) only after LOAD clusters. That is the single
// constraint that matters -- R4 proved regalloc sinks loads below consumes
// (VGPR=40, double-buffer collapsed); a fence after each load batch forbids
// that sink. Consume-side fences removed (consume->later-load hoisting is
// harmless; in-buffer load->consume order is a data dep). Also a fresh draw
// in case the R7 container failures were source-triggered.
//  - float2 / CHUNK=256 / NCH=8: lowest-redundancy config (627 MB issued),
//    2048 one-wave blocks = 8 waves/CU
//  - 4 named buffers x G=4 steps: consume batch g while batch g+1..g+4 in
//    flight -> continuous ~16 loads outstanding per wave
//  - NT stores for out (keep L2/L3 for warm-up re-reads)
//  - numerics identical to R2/R5 (same per-channel FMA order, WARM=128)

constexpr int   T_DIM = 2048;
constexpr int   BD    = 32 * 1024;     // 32768 scalar channels
constexpr int   BD2   = BD / 2;        // 16384 float2 channels
constexpr float BETA  = 0.95f;
constexpr int   CHUNK = 256;           // time steps per block
constexpr int   WARM  = 128;           // warm-up steps (beta^128 ~ 1.4e-3)
constexpr int   NCH   = T_DIM / CHUNK; // 8
constexpr int   BLOCK = 64;
constexpr int   G     = 4;             // steps per buffer; 4 bufs -> 16 in flight

typedef float nt_f2 __attribute__((ext_vector_type(2)));

__global__ __launch_bounds__(BLOCK)
void li_kernel(const float2* __restrict__ x, float2* __restrict__ out) {
    const int    c   = blockIdx.x * BLOCK + threadIdx.x;  // float2 channel
    const int    t0  = blockIdx.y * CHUNK;
    const size_t STP = (size_t)G * BD2;

    float b0 = 0.0f, b1 = 0.0f;
    float2 vA[G], vB[G], vC[G], vD[G];

    // Load one G-batch at cursor p, then fence: loads may not sink below here.
#define LOADB(dst, p)                                                         \
    {                                                                         \
        _Pragma("unroll")                                                     \
        for (int i = 0; i < G; ++i) (dst)[i] = (p)[(size_t)i * BD2];          \
        __builtin_amdgcn_sched_barrier(0);                                    \
    }

    // Consume (warm-up: no store). No fence -- in-buffer order is a data dep.
#define CONSW(src)                                                            \
    {                                                                         \
        _Pragma("unroll")                                                     \
        for (int i = 0; i < G; ++i) {                                         \
            b0 = fmaf(BETA, b0, (src)[i].x);                                  \
            b1 = fmaf(BETA, b1, (src)[i].y);                                  \
        }                                                                     \
    }

    // Consume + NT-store. No fence.
#define CONSM(src, p)                                                         \
    {                                                                         \
        _Pragma("unroll")                                                     \
        for (int i = 0; i < G; ++i) {                                         \
            b0 = fmaf(BETA, b0, (src)[i].x);                                  \
            b1 = fmaf(BETA, b1, (src)[i].y);                                  \
            nt_f2 vv = {b0, b1};                                              \
            __builtin_nontemporal_store(                                      \
                vv, reinterpret_cast<nt_f2*>((p) + (size_t)i * BD2));         \
        }                                                                     \
    }

    // ---- warm-up: read-only scan of the preceding WARM steps ----
    if (blockIdx.y > 0) {
        const float2* pl = x + (size_t)(t0 - WARM) * BD2 + c;
        LOADB(vA, pl); pl += STP;
        LOADB(vB, pl); pl += STP;
        LOADB(vC, pl); pl += STP;
        LOADB(vD, pl); pl += STP;
        // WARM/G = 32 batches total; 4 preloaded; 7 steady iters load 4..31.
        for (int g = 0; g < WARM / G / 4 - 1; ++g) {
            CONSW(vA); LOADB(vA, pl); pl += STP;
            CONSW(vB); LOADB(vB, pl); pl += STP;
            CONSW(vC); LOADB(vC, pl); pl += STP;
            CONSW(vD); LOADB(vD, pl); pl += STP;
        }
        CONSW(vA); CONSW(vB); CONSW(vC); CONSW(vD);
    }

    // ---- main: scan CHUNK steps, store running state ----
    {
        const float2* pl = x   + (size_t)t0 * BD2 + c;
        float2*       ps = out + (size_t)t0 * BD2 + c;
        LOADB(vA, pl); pl += STP;
        LOADB(vB, pl); pl += STP;
        LOADB(vC, pl); pl += STP;
        LOADB(vD, pl); pl += STP;
        // CHUNK/G = 64 batches total; 4 preloaded; 15 steady iters load 4..63.
        for (int g = 0; g < CHUNK / G / 4 - 1; ++g) {
            CONSM(vA, ps); ps += STP; LOADB(vA, pl); pl += STP;
            CONSM(vB, ps); ps += STP; LOADB(vB, pl); pl += STP;
            CONSM(vC, ps); ps += STP; LOADB(vC, pl); pl += STP;
            CONSM(vD, ps); ps += STP; LOADB(vD, pl); pl += STP;
        }
        CONSM(vA, ps); ps += STP;
        CONSM(vB, ps); ps += STP;
        CONSM(vC, ps); ps += STP;
        CONSM(vD, ps); ps += STP;
    }

#undef LOADB
#undef CONSW
#undef CONSM
}

extern "C" void kernel_launch(void* const* d_in, const int* in_sizes, int n_in,
                              void* d_out, int out_size, void* d_ws, size_t ws_size,
                              hipStream_t stream) {
    const float2* x   = (const float2*)d_in[0];
    float2*       out = (float2*)d_out;

    dim3 block(BLOCK, 1, 1);
    dim3 grid(BD2 / BLOCK, NCH, 1);   // (256, 8) = 2048 blocks, 8 waves/CU
    li_kernel<<<grid, block, 0, stream>>>(x, out);
}